// Round 1
// baseline (867.713 us; speedup 1.0000x reference)
//
#include <hip/hip_runtime.h>
#include <hip/hip_bf16.h>

#define HD __device__ __forceinline__

// Ordered-uint encoding for float atomicMax (handles negatives).
HD unsigned enc_f(float f){ unsigned u=__float_as_uint(f); return (u&0x80000000u)? ~u : (u|0x80000000u); }
HD float dec_f(unsigned u){ return (u&0x80000000u)? __uint_as_float(u^0x80000000u) : __uint_as_float(~u); }

// ---------------- CSR build ----------------
__global__ void k_count(const int* __restrict__ dst, const float* __restrict__ ea,
                        int* cnt, float* easum, int E){
  int e = blockIdx.x*blockDim.x + threadIdx.x;
  if (e>=E) return;
  int d = dst[e];
  atomicAdd(&cnt[d],1);
  atomicAdd(&easum[d], ea[e]);
}

__global__ __launch_bounds__(1024) void k_scan(const int* __restrict__ cnt, int* offs, int N){
  __shared__ int lds[1024];
  __shared__ int running;
  if (threadIdx.x==0) running = 0;
  __syncthreads();
  for (int base=0; base<N; base+=1024){
    int i = base + (int)threadIdx.x;
    int v = (i<N)? cnt[i] : 0;
    lds[threadIdx.x] = v;
    __syncthreads();
    #pragma unroll
    for (int off=1; off<1024; off<<=1){
      int t = (threadIdx.x>=(unsigned)off)? lds[threadIdx.x-off] : 0;
      __syncthreads();
      lds[threadIdx.x] += t;
      __syncthreads();
    }
    int incl = lds[threadIdx.x];
    int total = lds[1023];
    if (i<N) offs[i] = running + incl - v;   // exclusive
    __syncthreads();
    if (threadIdx.x==0) running += total;
    __syncthreads();
  }
  if (threadIdx.x==0) offs[N] = running;
}

__global__ void k_scatter(const int* __restrict__ dst, const int* __restrict__ offs,
                          int* fill, int* csr, int E){
  int e = blockIdx.x*blockDim.x + threadIdx.x;
  if (e>=E) return;
  int d = dst[e];
  int p = offs[d] + atomicAdd(&fill[d],1);
  csr[p] = e;
}

__global__ void k_loopattr(const int* __restrict__ cnt, const float* __restrict__ easum,
                           float* la, int N){
  int n = blockIdx.x*blockDim.x + threadIdx.x;
  if (n>=N) return;
  la[n] = easum[n] / fmaxf((float)cnt[n], 1.f);
}

// wedot[h] = dot(We[0, h*64:...], ae[h,:])  (De==1)
__global__ __launch_bounds__(512) void k_wedot(const float* __restrict__ We1, const float* __restrict__ ae1,
                        const float* __restrict__ We2, const float* __restrict__ ae2,
                        float* wedot){
  int which = blockIdx.x;
  const float* We = which? We2 : We1;
  const float* ae = which? ae2 : ae1;
  int h = threadIdx.x>>6, lane = threadIdx.x&63;
  float p = We[h*64+lane]*ae[h*64+lane];
  #pragma unroll
  for (int o=32;o;o>>=1) p += __shfl_down(p,o);
  if (lane==0) wedot[which*8+h] = p;
}

// ---------------- fp32 tiled GEMM: C[M,N] = A[M,K] @ B[K,N] ----------------
__global__ __launch_bounds__(256) void k_gemm(const float* __restrict__ A, const float* __restrict__ B,
                      float* __restrict__ C, int M, int N, int K){
  __shared__ float As[16][65];   // As[k][m]
  __shared__ float Bs[16][65];   // Bs[k][n]
  const int tx = threadIdx.x & 15, ty = threadIdx.x >> 4;
  const int m0 = blockIdx.y*64, n0 = blockIdx.x*64;
  float acc[4][4] = {};
  for (int k0=0; k0<K; k0+=16){
    {
      int t = threadIdx.x;
      int r = t>>2, c4 = (t&3)<<2;
      int row = m0 + r;
      float4 v = make_float4(0.f,0.f,0.f,0.f);
      if (row < M) v = *(const float4*)(A + (size_t)row*K + k0 + c4);
      As[c4+0][r]=v.x; As[c4+1][r]=v.y; As[c4+2][r]=v.z; As[c4+3][r]=v.w;
      int rb = t>>4, cb = (t&15)<<2;
      float4 w = *(const float4*)(B + (size_t)(k0+rb)*N + n0 + cb);
      Bs[rb][cb+0]=w.x; Bs[rb][cb+1]=w.y; Bs[rb][cb+2]=w.z; Bs[rb][cb+3]=w.w;
    }
    __syncthreads();
    #pragma unroll
    for (int kk=0; kk<16; ++kk){
      float a[4], b[4];
      #pragma unroll
      for (int i=0;i<4;++i) a[i] = As[kk][ty*4+i];
      #pragma unroll
      for (int j=0;j<4;++j) b[j] = Bs[kk][tx*4+j];
      #pragma unroll
      for (int i=0;i<4;++i)
        #pragma unroll
        for (int j=0;j<4;++j)
          acc[i][j] += a[i]*b[j];
    }
    __syncthreads();
  }
  #pragma unroll
  for (int i=0;i<4;++i){
    int row = m0 + ty*4 + i;
    if (row < M){
      float4 v = make_float4(acc[i][0],acc[i][1],acc[i][2],acc[i][3]);
      *(float4*)(C + (size_t)row*N + n0 + tx*4) = v;
    }
  }
}

// alpha_src[n,h], alpha_dst[n,h]: wave h dots h[n, h*64:...] with a_src/a_dst
__global__ __launch_bounds__(512) void k_alpha_nodes(const float* __restrict__ h,
    const float* __restrict__ a_s, const float* __restrict__ a_d,
    float* asrc, float* adst, int N){
  int n = blockIdx.x;
  int hh = threadIdx.x>>6, lane = threadIdx.x&63;
  float hv = h[(size_t)n*512 + threadIdx.x];
  float s = hv * a_s[threadIdx.x];
  float d = hv * a_d[threadIdx.x];
  #pragma unroll
  for (int o=32;o;o>>=1){ s += __shfl_down(s,o); d += __shfl_down(d,o); }
  if (lane==0){ asrc[n*8+hh]=s; adst[n*8+hh]=d; }
}

__global__ void k_edge_alpha(const int* __restrict__ src, const int* __restrict__ dst,
    const float* __restrict__ ea, const float* __restrict__ asrc, const float* __restrict__ adst,
    const float* __restrict__ wedot, float* __restrict__ alpha, unsigned* amax, int E){
  int e = blockIdx.x*blockDim.x + threadIdx.x;
  if (e>=E) return;
  int s = src[e], d = dst[e];
  float eav = ea[e];
  #pragma unroll
  for (int h=0;h<8;++h){
    float a = asrc[s*8+h] + adst[d*8+h] + eav*wedot[h];
    a = a>0.f ? a : 0.2f*a;
    alpha[(size_t)e*8+h] = a;
    atomicMax(&amax[d*8+h], enc_f(a));
  }
}

__global__ void k_edge_ex(const int* __restrict__ dst, float* __restrict__ alpha,
                          const unsigned* __restrict__ amax, float* denom, int E){
  int e = blockIdx.x*blockDim.x + threadIdx.x;
  if (e>=E) return;
  int d = dst[e];
  #pragma unroll
  for (int h=0;h<8;++h){
    float m = dec_f(amax[d*8+h]);
    float x = expf(alpha[(size_t)e*8+h] - m);
    alpha[(size_t)e*8+h] = x;
    atomicAdd(&denom[d*8+h], x);
  }
}

__global__ void k_self_alpha(const float* __restrict__ asrc, const float* __restrict__ adst,
    const float* __restrict__ la, const float* __restrict__ wedot,
    float* aself, unsigned* amax, int NH){
  int i = blockIdx.x*blockDim.x + threadIdx.x;
  if (i>=NH) return;
  int n = i>>3, h = i&7;
  float a = asrc[i] + adst[i] + la[n]*wedot[h];
  a = a>0.f ? a : 0.2f*a;
  aself[i] = a;
  atomicMax(&amax[i], enc_f(a));
}

__global__ void k_self_ex(float* __restrict__ aself, const unsigned* __restrict__ amax,
                          float* denom, int NH){
  int i = blockIdx.x*blockDim.x + threadIdx.x;
  if (i>=NH) return;
  float x = expf(aself[i] - dec_f(amax[i]));
  aself[i] = x;
  atomicAdd(&denom[i], x);
}

// one wave per (node, head); lane = channel
__global__ __launch_bounds__(256) void k_aggregate(const float* __restrict__ h,
    const float* __restrict__ ex, const float* __restrict__ denom,
    const int* __restrict__ csr, const int* __restrict__ offs, const int* __restrict__ src,
    const float* __restrict__ bias, const float* __restrict__ exself,
    float* __restrict__ out, int N, int relu_flag, int self_flag){
  int gw = blockIdx.x*(blockDim.x>>6) + (threadIdx.x>>6);
  int lane = threadIdx.x & 63;
  int n = gw>>3, hh = gw&7;
  if (n>=N) return;
  int beg = offs[n], end = offs[n+1];
  float acc = 0.f;
  for (int p=beg; p<end; ++p){
    int e = csr[p];
    int s = src[e];
    acc += ex[(size_t)e*8+hh] * h[(size_t)s*512 + hh*64 + lane];
  }
  if (self_flag) acc += exself[n*8+hh] * h[(size_t)n*512 + hh*64 + lane];
  float val = acc/(denom[n*8+hh] + 1e-16f) + bias[hh*64+lane];
  if (relu_flag) val = fmaxf(val, 0.f);
  out[(size_t)n*512 + hh*64 + lane] = val;
}

// column mean: block = 512 threads (one per channel), each block covers 256 rows
__global__ __launch_bounds__(512) void k_colmean(const float* __restrict__ out2, float* __restrict__ o,
                          int N, float invN){
  int c = threadIdx.x;
  int n0 = blockIdx.x*256;
  int nend = min(n0+256, N);
  float s = 0.f;
  for (int n=n0;n<nend;++n) s += out2[(size_t)n*512 + c];
  atomicAdd(&o[c], s*invN);
}

extern "C" void kernel_launch(void* const* d_in, const int* in_sizes, int n_in,
                              void* d_out, int out_size, void* d_ws, size_t ws_size,
                              hipStream_t stream){
  const float* x   = (const float*)d_in[0];
  const int* eidx  = (const int*)d_in[1];
  const float* ea  = (const float*)d_in[2];
  const float* W1  = (const float*)d_in[3];
  const float* We1 = (const float*)d_in[4];
  const float* as1 = (const float*)d_in[5];
  const float* ad1 = (const float*)d_in[6];
  const float* ae1 = (const float*)d_in[7];
  const float* b1  = (const float*)d_in[8];
  const float* W2  = (const float*)d_in[9];
  const float* We2 = (const float*)d_in[10];
  const float* as2 = (const float*)d_in[11];
  const float* ad2 = (const float*)d_in[12];
  const float* ae2 = (const float*)d_in[13];
  const float* b2  = (const float*)d_in[14];
  float* outp = (float*)d_out;

  const int FIN = 128, D1 = 512, H = 8;
  const int N = in_sizes[0]/FIN;
  const int E = in_sizes[1]/2;
  const int* srcA = eidx;
  const int* dstA = eidx + E;

  char* ws = (char*)d_ws;
  size_t o = 0;
  auto alloc = [&](size_t bytes)->void*{
    void* p = ws + o; o = (o + bytes + 255) & ~(size_t)255; return p;
  };
  float* h1    = (float*)alloc((size_t)N*D1*4);   // layer1 features; reused as out2
  float* out1r = (float*)alloc((size_t)N*D1*4);   // relu(layer1 out)
  float* h2    = (float*)alloc((size_t)N*D1*4);
  float* alphaE= (float*)alloc((size_t)E*H*4);    // alpha then ex, both layers
  int*   csr   = (int*)  alloc((size_t)E*4);
  int*   offs  = (int*)  alloc((size_t)(N+1)*4);
  size_t zbeg = o;
  int*   cnt   = (int*)  alloc((size_t)N*4);
  int*   fill  = (int*)  alloc((size_t)N*4);
  float* easum = (float*)alloc((size_t)N*4);
  unsigned* amax1 = (unsigned*)alloc((size_t)N*H*4);
  float* den1  = (float*)alloc((size_t)N*H*4);
  unsigned* amax2 = (unsigned*)alloc((size_t)N*H*4);
  float* den2  = (float*)alloc((size_t)N*H*4);
  size_t zend = o;
  float* asrc  = (float*)alloc((size_t)N*H*4);
  float* adst  = (float*)alloc((size_t)N*H*4);
  float* la    = (float*)alloc((size_t)N*4);
  float* aself = (float*)alloc((size_t)N*H*4);
  float* wedot = (float*)alloc(64);
  (void)ws_size; (void)n_in;

  hipMemsetAsync(ws + zbeg, 0, zend - zbeg, stream);
  hipMemsetAsync(d_out, 0, (size_t)out_size*sizeof(float), stream);

  dim3 b256(256);
  int ge = (E+255)/256;
  int gnh = (N*H+255)/256;

  // CSR + self-loop attrs (edge_attr/dst are static per launch)
  k_count   <<<ge, b256, 0, stream>>>(dstA, ea, cnt, easum, E);
  k_scan    <<<1, 1024, 0, stream>>>(cnt, offs, N);
  k_scatter <<<ge, b256, 0, stream>>>(dstA, offs, fill, csr, E);
  k_loopattr<<<(N+255)/256, b256, 0, stream>>>(cnt, easum, la, N);
  k_wedot   <<<2, 512, 0, stream>>>(We1, ae1, We2, ae2, wedot);

  // ---- layer 1 (no self loops) ----
  k_gemm<<<dim3(D1/64, (N+63)/64), b256, 0, stream>>>(x, W1, h1, N, D1, FIN);
  k_alpha_nodes<<<N, 512, 0, stream>>>(h1, as1, ad1, asrc, adst, N);
  k_edge_alpha<<<ge, b256, 0, stream>>>(srcA, dstA, ea, asrc, adst, wedot, alphaE, amax1, E);
  k_edge_ex<<<ge, b256, 0, stream>>>(dstA, alphaE, amax1, den1, E);
  k_aggregate<<<(N*H+3)/4, b256, 0, stream>>>(h1, alphaE, den1, csr, offs, srcA,
                                              b1, (const float*)nullptr, out1r, N, 1, 0);

  // ---- layer 2 (self loops, fill='mean') ----
  k_gemm<<<dim3(D1/64, (N+63)/64), b256, 0, stream>>>(out1r, W2, h2, N, D1, D1);
  k_alpha_nodes<<<N, 512, 0, stream>>>(h2, as2, ad2, asrc, adst, N);
  k_edge_alpha<<<ge, b256, 0, stream>>>(srcA, dstA, ea, asrc, adst, wedot+8, alphaE, amax2, E);
  k_self_alpha<<<gnh, b256, 0, stream>>>(asrc, adst, la, wedot+8, aself, amax2, N*H);
  k_edge_ex<<<ge, b256, 0, stream>>>(dstA, alphaE, amax2, den2, E);
  k_self_ex<<<gnh, b256, 0, stream>>>(aself, amax2, den2, N*H);
  k_aggregate<<<(N*H+3)/4, b256, 0, stream>>>(h2, alphaE, den2, csr, offs, srcA,
                                              b2, aself, h1 /*out2*/, N, 0, 1);

  // ---- mean over nodes ----
  k_colmean<<<(N+255)/256, 512, 0, stream>>>(h1, outp, N, 1.0f/(float)N);
}

// Round 2
// 398.747 us; speedup vs baseline: 2.1761x; 2.1761x over previous
//
#include <hip/hip_runtime.h>
#include <hip/hip_bf16.h>

#define HD __device__ __forceinline__

// ---------------- CSR build ----------------
__global__ void k_count(const int* __restrict__ dst, const float* __restrict__ ea,
                        int* cnt, float* easum, int E){
  int e = blockIdx.x*blockDim.x + threadIdx.x;
  if (e>=E) return;
  int d = dst[e];
  atomicAdd(&cnt[d],1);
  atomicAdd(&easum[d], ea[e]);
}

// two-level scan, one block
__global__ __launch_bounds__(1024) void k_scan(const int* __restrict__ cnt, int* offs, int N){
  __shared__ int lds[1024];
  const int chunk = (N + 1023)/1024;
  const int b = threadIdx.x*chunk;
  int s = 0;
  for (int i=0;i<chunk;++i){ int idx=b+i; if (idx<N) s += cnt[idx]; }
  lds[threadIdx.x] = s;
  __syncthreads();
  #pragma unroll
  for (int off=1; off<1024; off<<=1){
    int t = (threadIdx.x>=(unsigned)off)? lds[threadIdx.x-off] : 0;
    __syncthreads();
    lds[threadIdx.x] += t;
    __syncthreads();
  }
  int excl = lds[threadIdx.x] - s;   // exclusive prefix of this thread's chunk
  for (int i=0;i<chunk;++i){
    int idx=b+i;
    if (idx<N){ offs[idx] = excl; excl += cnt[idx]; }
  }
  if (threadIdx.x==1023) offs[N] = lds[1023];
}

// scatter edges into CSR order, pre-joining src index and edge_attr
__global__ void k_scatter(const int* __restrict__ src, const int* __restrict__ dst,
                          const float* __restrict__ ea, const int* __restrict__ offs,
                          int* fill, int* srcs, float* eas, int E){
  int e = blockIdx.x*blockDim.x + threadIdx.x;
  if (e>=E) return;
  int d = dst[e];
  int p = offs[d] + atomicAdd(&fill[d],1);
  srcs[p] = src[e];
  eas[p]  = ea[e];
}

__global__ void k_loopattr(const int* __restrict__ cnt, const float* __restrict__ easum,
                           float* la, int N){
  int n = blockIdx.x*blockDim.x + threadIdx.x;
  if (n>=N) return;
  la[n] = easum[n] / fmaxf((float)cnt[n], 1.f);
}

// wedot[h] = dot(We[0, h*64:...], ae[h,:])  (De==1)
__global__ __launch_bounds__(512) void k_wedot(const float* __restrict__ We1, const float* __restrict__ ae1,
                        const float* __restrict__ We2, const float* __restrict__ ae2,
                        float* wedot){
  int which = blockIdx.x;
  const float* We = which? We2 : We1;
  const float* ae = which? ae2 : ae1;
  int hh = threadIdx.x>>6, lane = threadIdx.x&63;
  float p = We[hh*64+lane]*ae[hh*64+lane];
  #pragma unroll
  for (int o=32;o;o>>=1) p += __shfl_down(p,o);
  if (lane==0) wedot[which*8+hh] = p;
}

// ---------------- fp32 tiled GEMM: C[M,N] = A[M,K] @ B[K,N] ----------------
__global__ __launch_bounds__(256) void k_gemm(const float* __restrict__ A, const float* __restrict__ B,
                      float* __restrict__ C, int M, int N, int K){
  __shared__ float As[16][65];   // As[k][m]
  __shared__ float Bs[16][65];   // Bs[k][n]
  const int tx = threadIdx.x & 15, ty = threadIdx.x >> 4;
  const int m0 = blockIdx.y*64, n0 = blockIdx.x*64;
  float acc[4][4] = {};
  for (int k0=0; k0<K; k0+=16){
    {
      int t = threadIdx.x;
      int r = t>>2, c4 = (t&3)<<2;
      int row = m0 + r;
      float4 v = make_float4(0.f,0.f,0.f,0.f);
      if (row < M) v = *(const float4*)(A + (size_t)row*K + k0 + c4);
      As[c4+0][r]=v.x; As[c4+1][r]=v.y; As[c4+2][r]=v.z; As[c4+3][r]=v.w;
      int rb = t>>4, cb = (t&15)<<2;
      float4 w = *(const float4*)(B + (size_t)(k0+rb)*N + n0 + cb);
      Bs[rb][cb+0]=w.x; Bs[rb][cb+1]=w.y; Bs[rb][cb+2]=w.z; Bs[rb][cb+3]=w.w;
    }
    __syncthreads();
    #pragma unroll
    for (int kk=0; kk<16; ++kk){
      float a[4], b[4];
      #pragma unroll
      for (int i=0;i<4;++i) a[i] = As[kk][ty*4+i];
      #pragma unroll
      for (int j=0;j<4;++j) b[j] = Bs[kk][tx*4+j];
      #pragma unroll
      for (int i=0;i<4;++i)
        #pragma unroll
        for (int j=0;j<4;++j)
          acc[i][j] += a[i]*b[j];
    }
    __syncthreads();
  }
  #pragma unroll
  for (int i=0;i<4;++i){
    int row = m0 + ty*4 + i;
    if (row < M){
      float4 v = make_float4(acc[i][0],acc[i][1],acc[i][2],acc[i][3]);
      *(float4*)(C + (size_t)row*N + n0 + tx*4) = v;
    }
  }
}

// alpha_src[n,h], alpha_dst[n,h]: wave hh dots h[n, hh*64:...] with a_src/a_dst
__global__ __launch_bounds__(512) void k_alpha_nodes(const float* __restrict__ h,
    const float* __restrict__ a_s, const float* __restrict__ a_d,
    float* asrc, float* adst, int N){
  int n = blockIdx.x;
  int hh = threadIdx.x>>6, lane = threadIdx.x&63;
  float hv = h[(size_t)n*512 + threadIdx.x];
  float s = hv * a_s[threadIdx.x];
  float d = hv * a_d[threadIdx.x];
  #pragma unroll
  for (int o=32;o;o>>=1){ s += __shfl_down(s,o); d += __shfl_down(d,o); }
  if (lane==0){ asrc[n*8+hh]=s; adst[n*8+hh]=d; }
}

// ---------------- CSR-ordered per-node softmax (no atomics) ----------------
// wave per node; lane = (esub=lane>>3, head=lane&7). Stores NORMALIZED attn
// into exn[p*8+h] (CSR order) and self-attn into aselfn[n*8+h].
__global__ __launch_bounds__(256) void k_softmax(
    const int* __restrict__ srcs, const float* __restrict__ eas,
    const int* __restrict__ offs,
    const float* __restrict__ asrc, const float* __restrict__ adst,
    const float* __restrict__ wedot, const float* __restrict__ la,
    float* __restrict__ exn, float* __restrict__ aselfn,
    int N, int self_flag){
  int n = blockIdx.x*4 + (threadIdx.x>>6);
  if (n>=N) return;
  int lane = threadIdx.x&63;
  int hh = lane&7, esub = lane>>3;
  int beg = offs[n], end = offs[n+1];
  float wd = wedot[hh];
  float adn = adst[n*8+hh];

  // pass 1: alpha -> exn (raw), running max
  float mx = -1e30f;
  for (int p0=beg; p0<end; p0+=8){
    int p = p0 + esub;
    if (p<end){
      int s = srcs[p];
      float a = asrc[s*8+hh] + adn + eas[p]*wd;
      a = a>0.f ? a : 0.2f*a;
      exn[(size_t)p*8+hh] = a;
      mx = fmaxf(mx, a);
    }
  }
  float aself = 0.f;
  if (self_flag){
    float a = asrc[n*8+hh] + adn + la[n]*wd;
    aself = a>0.f ? a : 0.2f*a;
    if (esub==0) mx = fmaxf(mx, aself);
  }
  mx = fmaxf(mx, __shfl_xor(mx, 8));
  mx = fmaxf(mx, __shfl_xor(mx, 16));
  mx = fmaxf(mx, __shfl_xor(mx, 32));

  // pass 2: exp, running sum
  float sum = 0.f;
  for (int p0=beg; p0<end; p0+=8){
    int p = p0 + esub;
    if (p<end){
      float x = __expf(exn[(size_t)p*8+hh] - mx);
      exn[(size_t)p*8+hh] = x;
      sum += x;
    }
  }
  float xs = 0.f;
  if (self_flag && esub==0){ xs = __expf(aself - mx); sum += xs; }
  sum += __shfl_xor(sum, 8);
  sum += __shfl_xor(sum, 16);
  sum += __shfl_xor(sum, 32);
  float inv = 1.f/(sum + 1e-16f);

  // pass 3: normalize in place
  for (int p0=beg; p0<end; p0+=8){
    int p = p0 + esub;
    if (p<end) exn[(size_t)p*8+hh] *= inv;
  }
  if (self_flag && esub==0) aselfn[n*8+hh] = xs*inv;
}

// ---------------- aggregate: wave per (node, head-quad), float4 lanes -------
__global__ __launch_bounds__(256) void k_aggregate(const float* __restrict__ h,
    const float* __restrict__ exn, const int* __restrict__ srcs,
    const int* __restrict__ offs, const float* __restrict__ bias,
    const float* __restrict__ aselfn, float* __restrict__ out,
    int N, int relu_flag, int self_flag){
  int gw = blockIdx.x*4 + (threadIdx.x>>6);
  if (gw >= 2*N) return;
  int n = gw>>1, hq = gw&1;
  int lane = threadIdx.x&63;
  int sub = lane>>4;                 // head within quad
  int coff = hq*256 + lane*4;        // channel offset within 512
  int beg = offs[n], end = offs[n+1];
  float4 acc = make_float4(0.f,0.f,0.f,0.f);
  int p = beg;
  for (; p+2<=end; p+=2){
    int s0 = srcs[p], s1 = srcs[p+1];
    float e0 = exn[(size_t)p*8 + hq*4 + sub];
    float e1 = exn[(size_t)(p+1)*8 + hq*4 + sub];
    float4 h0 = *(const float4*)(h + (size_t)s0*512 + coff);
    float4 h1 = *(const float4*)(h + (size_t)s1*512 + coff);
    acc.x = fmaf(e0,h0.x, fmaf(e1,h1.x, acc.x));
    acc.y = fmaf(e0,h0.y, fmaf(e1,h1.y, acc.y));
    acc.z = fmaf(e0,h0.z, fmaf(e1,h1.z, acc.z));
    acc.w = fmaf(e0,h0.w, fmaf(e1,h1.w, acc.w));
  }
  if (p<end){
    int s0 = srcs[p];
    float e0 = exn[(size_t)p*8 + hq*4 + sub];
    float4 h0 = *(const float4*)(h + (size_t)s0*512 + coff);
    acc.x = fmaf(e0,h0.x,acc.x); acc.y = fmaf(e0,h0.y,acc.y);
    acc.z = fmaf(e0,h0.z,acc.z); acc.w = fmaf(e0,h0.w,acc.w);
  }
  if (self_flag){
    float es = aselfn[n*8 + hq*4 + sub];
    float4 hv = *(const float4*)(h + (size_t)n*512 + coff);
    acc.x = fmaf(es,hv.x,acc.x); acc.y = fmaf(es,hv.y,acc.y);
    acc.z = fmaf(es,hv.z,acc.z); acc.w = fmaf(es,hv.w,acc.w);
  }
  float4 bv = *(const float4*)(bias + coff);
  float4 v = make_float4(acc.x+bv.x, acc.y+bv.y, acc.z+bv.z, acc.w+bv.w);
  if (relu_flag){
    v.x=fmaxf(v.x,0.f); v.y=fmaxf(v.y,0.f); v.z=fmaxf(v.z,0.f); v.w=fmaxf(v.w,0.f);
  }
  *(float4*)(out + (size_t)n*512 + coff) = v;
}

// column mean: block = 512 threads (one per channel), each block covers 256 rows
__global__ __launch_bounds__(512) void k_colmean(const float* __restrict__ out2, float* __restrict__ o,
                          int N, float invN){
  int c = threadIdx.x;
  int n0 = blockIdx.x*256;
  int nend = min(n0+256, N);
  float s = 0.f;
  for (int n=n0;n<nend;++n) s += out2[(size_t)n*512 + c];
  atomicAdd(&o[c], s*invN);
}

extern "C" void kernel_launch(void* const* d_in, const int* in_sizes, int n_in,
                              void* d_out, int out_size, void* d_ws, size_t ws_size,
                              hipStream_t stream){
  const float* x   = (const float*)d_in[0];
  const int* eidx  = (const int*)d_in[1];
  const float* ea  = (const float*)d_in[2];
  const float* W1  = (const float*)d_in[3];
  const float* We1 = (const float*)d_in[4];
  const float* as1 = (const float*)d_in[5];
  const float* ad1 = (const float*)d_in[6];
  const float* ae1 = (const float*)d_in[7];
  const float* b1  = (const float*)d_in[8];
  const float* W2  = (const float*)d_in[9];
  const float* We2 = (const float*)d_in[10];
  const float* as2 = (const float*)d_in[11];
  const float* ad2 = (const float*)d_in[12];
  const float* ae2 = (const float*)d_in[13];
  const float* b2  = (const float*)d_in[14];
  float* outp = (float*)d_out;

  const int FIN = 128, D1 = 512;
  const int N = in_sizes[0]/FIN;
  const int E = in_sizes[1]/2;
  const int* srcA = eidx;
  const int* dstA = eidx + E;

  char* ws = (char*)d_ws;
  size_t o = 0;
  auto alloc = [&](size_t bytes)->void*{
    void* p = ws + o; o = (o + bytes + 255) & ~(size_t)255; return p;
  };
  float* h1    = (float*)alloc((size_t)N*D1*4);   // layer1 features; reused as out2
  float* out1r = (float*)alloc((size_t)N*D1*4);   // relu(layer1 out)
  float* h2    = (float*)alloc((size_t)N*D1*4);
  float* exn   = (float*)alloc((size_t)E*8*4);    // normalized attn, CSR order
  int*   srcs  = (int*)  alloc((size_t)E*4);      // src idx, CSR order
  float* eas   = (float*)alloc((size_t)E*4);      // edge_attr, CSR order
  int*   offs  = (int*)  alloc((size_t)(N+1)*4);
  size_t zbeg = o;
  int*   cnt   = (int*)  alloc((size_t)N*4);
  int*   fill  = (int*)  alloc((size_t)N*4);
  float* easum = (float*)alloc((size_t)N*4);
  size_t zend = o;
  float* asrc  = (float*)alloc((size_t)N*8*4);
  float* adst  = (float*)alloc((size_t)N*8*4);
  float* la    = (float*)alloc((size_t)N*4);
  float* aselfn= (float*)alloc((size_t)N*8*4);
  float* wedot = (float*)alloc(64);
  (void)ws_size; (void)n_in;

  hipMemsetAsync(ws + zbeg, 0, zend - zbeg, stream);
  hipMemsetAsync(d_out, 0, (size_t)out_size*sizeof(float), stream);

  dim3 b256(256);
  int ge = (E+255)/256;
  int gn4 = (N+3)/4;

  // CSR build (pre-joined) + self-loop attrs
  k_count   <<<ge, b256, 0, stream>>>(dstA, ea, cnt, easum, E);
  k_scan    <<<1, 1024, 0, stream>>>(cnt, offs, N);
  k_scatter <<<ge, b256, 0, stream>>>(srcA, dstA, ea, offs, fill, srcs, eas, E);
  k_loopattr<<<(N+255)/256, b256, 0, stream>>>(cnt, easum, la, N);
  k_wedot   <<<2, 512, 0, stream>>>(We1, ae1, We2, ae2, wedot);

  // ---- layer 1 (no self loops) ----
  k_gemm<<<dim3(D1/64, (N+63)/64), b256, 0, stream>>>(x, W1, h1, N, D1, FIN);
  k_alpha_nodes<<<N, 512, 0, stream>>>(h1, as1, ad1, asrc, adst, N);
  k_softmax<<<gn4, b256, 0, stream>>>(srcs, eas, offs, asrc, adst, wedot, la,
                                      exn, aselfn, N, 0);
  k_aggregate<<<(2*N+3)/4, b256, 0, stream>>>(h1, exn, srcs, offs, b1,
                                              aselfn, out1r, N, 1, 0);

  // ---- layer 2 (self loops, fill='mean') ----
  k_gemm<<<dim3(D1/64, (N+63)/64), b256, 0, stream>>>(out1r, W2, h2, N, D1, D1);
  k_alpha_nodes<<<N, 512, 0, stream>>>(h2, as2, ad2, asrc, adst, N);
  k_softmax<<<gn4, b256, 0, stream>>>(srcs, eas, offs, asrc, adst, wedot+8, la,
                                      exn, aselfn, N, 1);
  k_aggregate<<<(2*N+3)/4, b256, 0, stream>>>(h2, exn, srcs, offs, b2,
                                              aselfn, h1 /*out2*/, N, 0, 1);

  // ---- mean over nodes ----
  k_colmean<<<(N+255)/256, 512, 0, stream>>>(h1, outp, N, 1.0f/(float)N);
}

// Round 3
// 297.128 us; speedup vs baseline: 2.9203x; 1.3420x over previous
//
#include <hip/hip_runtime.h>
#include <hip/hip_bf16.h>

#define HD __device__ __forceinline__
typedef unsigned short u16;
typedef __attribute__((ext_vector_type(8))) short bf16x8;
typedef __attribute__((ext_vector_type(4))) float f32x4;

// round-to-nearest-even fp32 -> bf16 bits
HD u16 f2b(float f){
  unsigned u = __float_as_uint(f);
  unsigned r = (u + 0x7fffu + ((u>>16)&1u)) >> 16;
  return (u16)r;
}

// ---------------- CSR build ----------------
__global__ void k_count(const int* __restrict__ dst, const float* __restrict__ ea,
                        int* cnt, float* easum, int E){
  int e = blockIdx.x*blockDim.x + threadIdx.x;
  if (e>=E) return;
  int d = dst[e];
  atomicAdd(&cnt[d],1);
  atomicAdd(&easum[d], ea[e]);
}

// two-level scan, one block
__global__ __launch_bounds__(1024) void k_scan(const int* __restrict__ cnt, int* offs, int N){
  __shared__ int lds[1024];
  const int chunk = (N + 1023)/1024;
  const int b = threadIdx.x*chunk;
  int s = 0;
  for (int i=0;i<chunk;++i){ int idx=b+i; if (idx<N) s += cnt[idx]; }
  lds[threadIdx.x] = s;
  __syncthreads();
  #pragma unroll
  for (int off=1; off<1024; off<<=1){
    int t = (threadIdx.x>=(unsigned)off)? lds[threadIdx.x-off] : 0;
    __syncthreads();
    lds[threadIdx.x] += t;
    __syncthreads();
  }
  int excl = lds[threadIdx.x] - s;
  for (int i=0;i<chunk;++i){
    int idx=b+i;
    if (idx<N){ offs[idx] = excl; excl += cnt[idx]; }
  }
  if (threadIdx.x==1023) offs[N] = lds[1023];
}

__global__ void k_scatter(const int* __restrict__ src, const int* __restrict__ dst,
                          const float* __restrict__ ea, const int* __restrict__ offs,
                          int* fill, int* srcs, float* eas, int E){
  int e = blockIdx.x*blockDim.x + threadIdx.x;
  if (e>=E) return;
  int d = dst[e];
  int p = offs[d] + atomicAdd(&fill[d],1);
  srcs[p] = src[e];
  eas[p]  = ea[e];
}

__global__ void k_loopattr(const int* __restrict__ cnt, const float* __restrict__ easum,
                           float* la, int N){
  int n = blockIdx.x*blockDim.x + threadIdx.x;
  if (n>=N) return;
  la[n] = easum[n] / fmaxf((float)cnt[n], 1.f);
}

__global__ __launch_bounds__(512) void k_wedot(const float* __restrict__ We1, const float* __restrict__ ae1,
                        const float* __restrict__ We2, const float* __restrict__ ae2,
                        float* wedot){
  int which = blockIdx.x;
  const float* We = which? We2 : We1;
  const float* ae = which? ae2 : ae1;
  int hh = threadIdx.x>>6, lane = threadIdx.x&63;
  float p = We[hh*64+lane]*ae[hh*64+lane];
  #pragma unroll
  for (int o=32;o;o>>=1) p += __shfl_down(p,o);
  if (lane==0) wedot[which*8+hh] = p;
}

// ---------------- casts ----------------
__global__ void k_cast_bf16(const float* __restrict__ in, u16* __restrict__ out, int total4){
  int i = (blockIdx.x*blockDim.x + threadIdx.x);
  if (i>=total4) return;
  float4 v = *(const float4*)(in + (size_t)i*4);
  ushort4 o; o.x=f2b(v.x); o.y=f2b(v.y); o.z=f2b(v.z); o.w=f2b(v.w);
  *(ushort4*)(out + (size_t)i*4) = o;
}

// W[K][N] fp32 -> Wt[N][K] bf16, 64x64 tiles
__global__ __launch_bounds__(256) void k_transpose_cast(const float* __restrict__ W,
                                                        u16* __restrict__ Wt, int K, int N){
  __shared__ float T[64][65];
  int k0 = blockIdx.y*64, n0 = blockIdx.x*64;
  #pragma unroll
  for (int i=0;i<16;++i){
    int id = i*256 + threadIdx.x;
    int r = id>>6, c = id&63;
    T[r][c] = W[(size_t)(k0+r)*N + n0 + c];
  }
  __syncthreads();
  #pragma unroll
  for (int i=0;i<16;++i){
    int id = i*256 + threadIdx.x;
    int rr = id>>6, cc = id&63;
    Wt[(size_t)(n0+rr)*K + k0 + cc] = f2b(T[cc][rr]);
  }
}

// ---------------- bf16 MFMA GEMM: C[M,N] = A[M,K] @ Bt[N,K]^T ----------------
// tile 128x64, BK=32, 256 threads = 4 waves in 2x2
__global__ __launch_bounds__(256) void k_gemm_mfma(
    const u16* __restrict__ A, const u16* __restrict__ Bt,
    float* __restrict__ C, int M, int N, int K){
  __shared__ char lds[(128+64)*80];   // row stride 80B (20 dwords) - conflict-free
  char* As = lds;
  char* Bs = lds + 128*80;
  const int tid = threadIdx.x;
  const int lane = tid & 63, w = tid >> 6;
  const int wr = w >> 1, wc = w & 1;
  const int l15 = lane & 15, l4 = lane >> 4;
  const int m0 = blockIdx.y*128, n0 = blockIdx.x*64;

  f32x4 acc[4][2] = {};
  int aoff[4], boff[2];
  #pragma unroll
  for (int i=0;i<4;++i) aoff[i] = (wr*64 + i*16 + l15)*80 + l4*16;
  #pragma unroll
  for (int j=0;j<2;++j) boff[j] = (wc*32 + j*16 + l15)*80 + l4*16;

  for (int k0=0; k0<K; k0+=32){
    // stage A: 512 chunks of 16B, 2 per thread
    #pragma unroll
    for (int i=0;i<2;++i){
      int cid = tid*2+i;
      int r = cid>>2, c = cid&3;
      int row = m0 + r;
      float4 v = make_float4(0.f,0.f,0.f,0.f);
      if (row < M) v = *(const float4*)(A + (size_t)row*K + k0 + c*8);
      *(float4*)(As + r*80 + c*16) = v;
    }
    // stage B: 256 chunks
    {
      int r = tid>>2, c = tid&3;
      float4 v = *(const float4*)(Bt + (size_t)(n0+r)*K + k0 + c*8);
      *(float4*)(Bs + r*80 + c*16) = v;
    }
    __syncthreads();
    bf16x8 a[4], b[2];
    #pragma unroll
    for (int i=0;i<4;++i) a[i] = *reinterpret_cast<const bf16x8*>(As + aoff[i]);
    #pragma unroll
    for (int j=0;j<2;++j) b[j] = *reinterpret_cast<const bf16x8*>(Bs + boff[j]);
    #pragma unroll
    for (int i=0;i<4;++i)
      #pragma unroll
      for (int j=0;j<2;++j)
        acc[i][j] = __builtin_amdgcn_mfma_f32_16x16x32_bf16(a[i], b[j], acc[i][j], 0,0,0);
    __syncthreads();
  }
  // epilogue: C[row][col], row=(lane>>4)*4+reg, col=lane&15
  #pragma unroll
  for (int i=0;i<4;++i){
    #pragma unroll
    for (int j=0;j<2;++j){
      #pragma unroll
      for (int r=0;r<4;++r){
        int row = m0 + wr*64 + i*16 + l4*4 + r;
        int col = n0 + wc*32 + j*16 + l15;
        if (row < M) C[(size_t)row*N + col] = acc[i][j][r];
      }
    }
  }
}

// alpha_src[n,h], alpha_dst[n,h]
__global__ __launch_bounds__(512) void k_alpha_nodes(const float* __restrict__ h,
    const float* __restrict__ a_s, const float* __restrict__ a_d,
    float* asrc, float* adst, int N){
  int n = blockIdx.x;
  int hh = threadIdx.x>>6, lane = threadIdx.x&63;
  float hv = h[(size_t)n*512 + threadIdx.x];
  float s = hv * a_s[threadIdx.x];
  float d = hv * a_d[threadIdx.x];
  #pragma unroll
  for (int o=32;o;o>>=1){ s += __shfl_down(s,o); d += __shfl_down(d,o); }
  if (lane==0){ asrc[n*8+hh]=s; adst[n*8+hh]=d; }
}

// ---------------- CSR-ordered per-node softmax ----------------
__global__ __launch_bounds__(256) void k_softmax(
    const int* __restrict__ srcs, const float* __restrict__ eas,
    const int* __restrict__ offs,
    const float* __restrict__ asrc, const float* __restrict__ adst,
    const float* __restrict__ wedot, const float* __restrict__ la,
    float* __restrict__ exn, float* __restrict__ aselfn,
    int N, int self_flag){
  int n = blockIdx.x*4 + (threadIdx.x>>6);
  if (n>=N) return;
  int lane = threadIdx.x&63;
  int hh = lane&7, esub = lane>>3;
  int beg = offs[n], end = offs[n+1];
  float wd = wedot[hh];
  float adn = adst[n*8+hh];

  float mx = -1e30f;
  for (int p0=beg; p0<end; p0+=8){
    int p = p0 + esub;
    if (p<end){
      int s = srcs[p];
      float a = asrc[s*8+hh] + adn + eas[p]*wd;
      a = a>0.f ? a : 0.2f*a;
      exn[(size_t)p*8+hh] = a;
      mx = fmaxf(mx, a);
    }
  }
  float aself = 0.f;
  if (self_flag){
    float a = asrc[n*8+hh] + adn + la[n]*wd;
    aself = a>0.f ? a : 0.2f*a;
    if (esub==0) mx = fmaxf(mx, aself);
  }
  mx = fmaxf(mx, __shfl_xor(mx, 8));
  mx = fmaxf(mx, __shfl_xor(mx, 16));
  mx = fmaxf(mx, __shfl_xor(mx, 32));

  float sum = 0.f;
  for (int p0=beg; p0<end; p0+=8){
    int p = p0 + esub;
    if (p<end){
      float x = __expf(exn[(size_t)p*8+hh] - mx);
      exn[(size_t)p*8+hh] = x;
      sum += x;
    }
  }
  float xs = 0.f;
  if (self_flag && esub==0){ xs = __expf(aself - mx); sum += xs; }
  sum += __shfl_xor(sum, 8);
  sum += __shfl_xor(sum, 16);
  sum += __shfl_xor(sum, 32);
  float inv = 1.f/(sum + 1e-16f);

  for (int p0=beg; p0<end; p0+=8){
    int p = p0 + esub;
    if (p<end) exn[(size_t)p*8+hh] *= inv;
  }
  if (self_flag && esub==0) aselfn[n*8+hh] = xs*inv;
}

// ---------------- aggregate: wave per (node, head-quad), float4 lanes -------
__global__ __launch_bounds__(256) void k_aggregate(const float* __restrict__ h,
    const float* __restrict__ exn, const int* __restrict__ srcs,
    const int* __restrict__ offs, const float* __restrict__ bias,
    const float* __restrict__ aselfn, float* __restrict__ out,
    u16* __restrict__ outb,
    int N, int relu_flag, int self_flag){
  int gw = blockIdx.x*4 + (threadIdx.x>>6);
  if (gw >= 2*N) return;
  int n = gw>>1, hq = gw&1;
  int lane = threadIdx.x&63;
  int sub = lane>>4;
  int coff = hq*256 + lane*4;
  int beg = offs[n], end = offs[n+1];
  float4 acc = make_float4(0.f,0.f,0.f,0.f);
  int p = beg;
  for (; p+2<=end; p+=2){
    int s0 = srcs[p], s1 = srcs[p+1];
    float e0 = exn[(size_t)p*8 + hq*4 + sub];
    float e1 = exn[(size_t)(p+1)*8 + hq*4 + sub];
    float4 h0 = *(const float4*)(h + (size_t)s0*512 + coff);
    float4 h1 = *(const float4*)(h + (size_t)s1*512 + coff);
    acc.x = fmaf(e0,h0.x, fmaf(e1,h1.x, acc.x));
    acc.y = fmaf(e0,h0.y, fmaf(e1,h1.y, acc.y));
    acc.z = fmaf(e0,h0.z, fmaf(e1,h1.z, acc.z));
    acc.w = fmaf(e0,h0.w, fmaf(e1,h1.w, acc.w));
  }
  if (p<end){
    int s0 = srcs[p];
    float e0 = exn[(size_t)p*8 + hq*4 + sub];
    float4 h0 = *(const float4*)(h + (size_t)s0*512 + coff);
    acc.x = fmaf(e0,h0.x,acc.x); acc.y = fmaf(e0,h0.y,acc.y);
    acc.z = fmaf(e0,h0.z,acc.z); acc.w = fmaf(e0,h0.w,acc.w);
  }
  if (self_flag){
    float es = aselfn[n*8 + hq*4 + sub];
    float4 hv = *(const float4*)(h + (size_t)n*512 + coff);
    acc.x = fmaf(es,hv.x,acc.x); acc.y = fmaf(es,hv.y,acc.y);
    acc.z = fmaf(es,hv.z,acc.z); acc.w = fmaf(es,hv.w,acc.w);
  }
  float4 bv = *(const float4*)(bias + coff);
  float4 v = make_float4(acc.x+bv.x, acc.y+bv.y, acc.z+bv.z, acc.w+bv.w);
  if (relu_flag){
    v.x=fmaxf(v.x,0.f); v.y=fmaxf(v.y,0.f); v.z=fmaxf(v.z,0.f); v.w=fmaxf(v.w,0.f);
  }
  if (outb){
    ushort4 o; o.x=f2b(v.x); o.y=f2b(v.y); o.z=f2b(v.z); o.w=f2b(v.w);
    *(ushort4*)(outb + (size_t)n*512 + coff) = o;
  } else {
    *(float4*)(out + (size_t)n*512 + coff) = v;
  }
}

__global__ __launch_bounds__(512) void k_colmean(const float* __restrict__ out2, float* __restrict__ o,
                          int N, float invN){
  int c = threadIdx.x;
  int n0 = blockIdx.x*256;
  int nend = min(n0+256, N);
  float s = 0.f;
  for (int n=n0;n<nend;++n) s += out2[(size_t)n*512 + c];
  atomicAdd(&o[c], s*invN);
}

extern "C" void kernel_launch(void* const* d_in, const int* in_sizes, int n_in,
                              void* d_out, int out_size, void* d_ws, size_t ws_size,
                              hipStream_t stream){
  const float* x   = (const float*)d_in[0];
  const int* eidx  = (const int*)d_in[1];
  const float* ea  = (const float*)d_in[2];
  const float* W1  = (const float*)d_in[3];
  const float* We1 = (const float*)d_in[4];
  const float* as1 = (const float*)d_in[5];
  const float* ad1 = (const float*)d_in[6];
  const float* ae1 = (const float*)d_in[7];
  const float* b1  = (const float*)d_in[8];
  const float* W2  = (const float*)d_in[9];
  const float* We2 = (const float*)d_in[10];
  const float* as2 = (const float*)d_in[11];
  const float* ad2 = (const float*)d_in[12];
  const float* ae2 = (const float*)d_in[13];
  const float* b2  = (const float*)d_in[14];
  float* outp = (float*)d_out;

  const int FIN = 128, D1 = 512;
  const int N = in_sizes[0]/FIN;
  const int E = in_sizes[1]/2;
  const int* srcA = eidx;
  const int* dstA = eidx + E;

  char* ws = (char*)d_ws;
  size_t o = 0;
  auto alloc = [&](size_t bytes)->void*{
    void* p = ws + o; o = (o + bytes + 255) & ~(size_t)255; return p;
  };
  float* h1    = (float*)alloc((size_t)N*D1*4);   // layer1 features; reused as out2
  float* h2    = (float*)alloc((size_t)N*D1*4);
  u16*   out1rb= (u16*)  alloc((size_t)N*D1*2);   // relu(layer1 out), bf16
  u16*   xb    = (u16*)  alloc((size_t)N*FIN*2);
  u16*   W1t   = (u16*)  alloc((size_t)D1*FIN*2); // [512][128]
  u16*   W2t   = (u16*)  alloc((size_t)D1*D1*2);  // [512][512]
  float* exn   = (float*)alloc((size_t)E*8*4);
  int*   srcs  = (int*)  alloc((size_t)E*4);
  float* eas   = (float*)alloc((size_t)E*4);
  int*   offs  = (int*)  alloc((size_t)(N+1)*4);
  size_t zbeg = o;
  int*   cnt   = (int*)  alloc((size_t)N*4);
  int*   fill  = (int*)  alloc((size_t)N*4);
  float* easum = (float*)alloc((size_t)N*4);
  size_t zend = o;
  float* asrc  = (float*)alloc((size_t)N*8*4);
  float* adst  = (float*)alloc((size_t)N*8*4);
  float* la    = (float*)alloc((size_t)N*4);
  float* aselfn= (float*)alloc((size_t)N*8*4);
  float* wedot = (float*)alloc(64);
  (void)ws_size; (void)n_in;

  hipMemsetAsync(ws + zbeg, 0, zend - zbeg, stream);
  hipMemsetAsync(d_out, 0, (size_t)out_size*sizeof(float), stream);

  dim3 b256(256);
  int ge = (E+255)/256;
  int gn4 = (N+3)/4;

  // CSR build + casts + weight transposes
  k_count   <<<ge, b256, 0, stream>>>(dstA, ea, cnt, easum, E);
  k_scan    <<<1, 1024, 0, stream>>>(cnt, offs, N);
  k_scatter <<<ge, b256, 0, stream>>>(srcA, dstA, ea, offs, fill, srcs, eas, E);
  k_loopattr<<<(N+255)/256, b256, 0, stream>>>(cnt, easum, la, N);
  k_wedot   <<<2, 512, 0, stream>>>(We1, ae1, We2, ae2, wedot);
  k_cast_bf16<<<((N*FIN/4)+255)/256, b256, 0, stream>>>(x, xb, N*FIN/4);
  k_transpose_cast<<<dim3(D1/64, FIN/64), b256, 0, stream>>>(W1, W1t, FIN, D1);
  k_transpose_cast<<<dim3(D1/64, D1/64),  b256, 0, stream>>>(W2, W2t, D1, D1);

  // ---- layer 1 (no self loops) ----
  k_gemm_mfma<<<dim3(D1/64, (N+127)/128), b256, 0, stream>>>(xb, W1t, h1, N, D1, FIN);
  k_alpha_nodes<<<N, 512, 0, stream>>>(h1, as1, ad1, asrc, adst, N);
  k_softmax<<<gn4, b256, 0, stream>>>(srcs, eas, offs, asrc, adst, wedot, la,
                                      exn, aselfn, N, 0);
  k_aggregate<<<(2*N+3)/4, b256, 0, stream>>>(h1, exn, srcs, offs, b1,
                                              (const float*)nullptr, (float*)nullptr,
                                              out1rb, N, 1, 0);

  // ---- layer 2 (self loops, fill='mean') ----
  k_gemm_mfma<<<dim3(D1/64, (N+127)/128), b256, 0, stream>>>(out1rb, W2t, h2, N, D1, D1);
  k_alpha_nodes<<<N, 512, 0, stream>>>(h2, as2, ad2, asrc, adst, N);
  k_softmax<<<gn4, b256, 0, stream>>>(srcs, eas, offs, asrc, adst, wedot+8, la,
                                      exn, aselfn, N, 1);
  k_aggregate<<<(2*N+3)/4, b256, 0, stream>>>(h2, exn, srcs, offs, b2,
                                              aselfn, h1 /*out2*/, (u16*)nullptr, N, 0, 1);

  // ---- mean over nodes ----
  k_colmean<<<(N+255)/256, 512, 0, stream>>>(h1, outp, N, 1.0f/(float)N);
}

// Round 4
// 253.257 us; speedup vs baseline: 3.4262x; 1.1732x over previous
//
#include <hip/hip_runtime.h>
#include <hip/hip_bf16.h>

#define HD __device__ __forceinline__
typedef unsigned short u16;
typedef __attribute__((ext_vector_type(8))) short bf16x8;
typedef __attribute__((ext_vector_type(4))) float f32x4;

// round-to-nearest-even fp32 -> bf16 bits
HD u16 f2b(float f){
  unsigned u = __float_as_uint(f);
  unsigned r = (u + 0x7fffu + ((u>>16)&1u)) >> 16;
  return (u16)r;
}

// ---------------- CSR build ----------------
__global__ void k_count(const int* __restrict__ dst, const float* __restrict__ ea,
                        int* cnt, float* easum, int E){
  int e = blockIdx.x*blockDim.x + threadIdx.x;
  if (e>=E) return;
  int d = dst[e];
  atomicAdd(&cnt[d],1);
  atomicAdd(&easum[d], ea[e]);
}

// two-level scan, one block
__global__ __launch_bounds__(1024) void k_scan(const int* __restrict__ cnt, int* offs, int N){
  __shared__ int lds[1024];
  const int chunk = (N + 1023)/1024;
  const int b = threadIdx.x*chunk;
  int s = 0;
  for (int i=0;i<chunk;++i){ int idx=b+i; if (idx<N) s += cnt[idx]; }
  lds[threadIdx.x] = s;
  __syncthreads();
  #pragma unroll
  for (int off=1; off<1024; off<<=1){
    int t = (threadIdx.x>=(unsigned)off)? lds[threadIdx.x-off] : 0;
    __syncthreads();
    lds[threadIdx.x] += t;
    __syncthreads();
  }
  int excl = lds[threadIdx.x] - s;
  for (int i=0;i<chunk;++i){
    int idx=b+i;
    if (idx<N){ offs[idx] = excl; excl += cnt[idx]; }
  }
  if (threadIdx.x==1023) offs[N] = lds[1023];
}

__global__ void k_scatter(const int* __restrict__ src, const int* __restrict__ dst,
                          const float* __restrict__ ea, const int* __restrict__ offs,
                          int* fill, int* srcs, float* eas, int E){
  int e = blockIdx.x*blockDim.x + threadIdx.x;
  if (e>=E) return;
  int d = dst[e];
  int p = offs[d] + atomicAdd(&fill[d],1);
  srcs[p] = src[e];
  eas[p]  = ea[e];
}

__global__ void k_loopattr(const int* __restrict__ cnt, const float* __restrict__ easum,
                           float* la, int N){
  int n = blockIdx.x*blockDim.x + threadIdx.x;
  if (n>=N) return;
  la[n] = easum[n] / fmaxf((float)cnt[n], 1.f);
}

__global__ __launch_bounds__(512) void k_wedot(const float* __restrict__ We1, const float* __restrict__ ae1,
                        const float* __restrict__ We2, const float* __restrict__ ae2,
                        float* wedot){
  int which = blockIdx.x;
  const float* We = which? We2 : We1;
  const float* ae = which? ae2 : ae1;
  int hh = threadIdx.x>>6, lane = threadIdx.x&63;
  float p = We[hh*64+lane]*ae[hh*64+lane];
  #pragma unroll
  for (int o=32;o;o>>=1) p += __shfl_down(p,o);
  if (lane==0) wedot[which*8+hh] = p;
}

// ---------------- casts ----------------
__global__ void k_cast_bf16(const float* __restrict__ in, u16* __restrict__ out, int total4){
  int i = (blockIdx.x*blockDim.x + threadIdx.x);
  if (i>=total4) return;
  float4 v = *(const float4*)(in + (size_t)i*4);
  ushort4 o; o.x=f2b(v.x); o.y=f2b(v.y); o.z=f2b(v.z); o.w=f2b(v.w);
  *(ushort4*)(out + (size_t)i*4) = o;
}

// W[K][N] fp32 -> Wt[N][K] bf16, 64x64 tiles
__global__ __launch_bounds__(256) void k_transpose_cast(const float* __restrict__ W,
                                                        u16* __restrict__ Wt, int K, int N){
  __shared__ float T[64][65];
  int k0 = blockIdx.y*64, n0 = blockIdx.x*64;
  #pragma unroll
  for (int i=0;i<16;++i){
    int id = i*256 + threadIdx.x;
    int r = id>>6, c = id&63;
    T[r][c] = W[(size_t)(k0+r)*N + n0 + c];
  }
  __syncthreads();
  #pragma unroll
  for (int i=0;i<16;++i){
    int id = i*256 + threadIdx.x;
    int rr = id>>6, cc = id&63;
    Wt[(size_t)(n0+rr)*K + k0 + cc] = f2b(T[cc][rr]);
  }
}

// ---------------- bf16 MFMA GEMM: C[M,N] = A[M,K] @ Bt[N,K]^T ----------------
// tile 128x64, BK=32, 256 threads = 4 waves in 2x2
__global__ __launch_bounds__(256) void k_gemm_mfma(
    const u16* __restrict__ A, const u16* __restrict__ Bt,
    float* __restrict__ C, int M, int N, int K){
  __shared__ char lds[(128+64)*80];   // row stride 80B (20 dwords) - conflict-free
  char* As = lds;
  char* Bs = lds + 128*80;
  const int tid = threadIdx.x;
  const int lane = tid & 63, w = tid >> 6;
  const int wr = w >> 1, wc = w & 1;
  const int l15 = lane & 15, l4 = lane >> 4;
  const int m0 = blockIdx.y*128, n0 = blockIdx.x*64;

  f32x4 acc[4][2] = {};
  int aoff[4], boff[2];
  #pragma unroll
  for (int i=0;i<4;++i) aoff[i] = (wr*64 + i*16 + l15)*80 + l4*16;
  #pragma unroll
  for (int j=0;j<2;++j) boff[j] = (wc*32 + j*16 + l15)*80 + l4*16;

  for (int k0=0; k0<K; k0+=32){
    // stage A: 512 chunks of 16B, 2 per thread
    #pragma unroll
    for (int i=0;i<2;++i){
      int cid = tid*2+i;
      int r = cid>>2, c = cid&3;
      int row = m0 + r;
      float4 v = make_float4(0.f,0.f,0.f,0.f);
      if (row < M) v = *(const float4*)(A + (size_t)row*K + k0 + c*8);
      *(float4*)(As + r*80 + c*16) = v;
    }
    // stage B: 256 chunks
    {
      int r = tid>>2, c = tid&3;
      float4 v = *(const float4*)(Bt + (size_t)(n0+r)*K + k0 + c*8);
      *(float4*)(Bs + r*80 + c*16) = v;
    }
    __syncthreads();
    bf16x8 a[4], b[2];
    #pragma unroll
    for (int i=0;i<4;++i) a[i] = *reinterpret_cast<const bf16x8*>(As + aoff[i]);
    #pragma unroll
    for (int j=0;j<2;++j) b[j] = *reinterpret_cast<const bf16x8*>(Bs + boff[j]);
    #pragma unroll
    for (int i=0;i<4;++i)
      #pragma unroll
      for (int j=0;j<2;++j)
        acc[i][j] = __builtin_amdgcn_mfma_f32_16x16x32_bf16(a[i], b[j], acc[i][j], 0,0,0);
    __syncthreads();
  }
  // epilogue: C[row][col], row=(lane>>4)*4+reg, col=lane&15
  #pragma unroll
  for (int i=0;i<4;++i){
    #pragma unroll
    for (int j=0;j<2;++j){
      #pragma unroll
      for (int r=0;r<4;++r){
        int row = m0 + wr*64 + i*16 + l4*4 + r;
        int col = n0 + wc*32 + j*16 + l15;
        if (row < M) C[(size_t)row*N + col] = acc[i][j][r];
      }
    }
  }
}

// alpha_src[n,h], alpha_dst[n,h]
__global__ __launch_bounds__(512) void k_alpha_nodes(const float* __restrict__ h,
    const float* __restrict__ a_s, const float* __restrict__ a_d,
    float* asrc, float* adst, int N){
  int n = blockIdx.x;
  int hh = threadIdx.x>>6, lane = threadIdx.x&63;
  float hv = h[(size_t)n*512 + threadIdx.x];
  float s = hv * a_s[threadIdx.x];
  float d = hv * a_d[threadIdx.x];
  #pragma unroll
  for (int o=32;o;o>>=1){ s += __shfl_down(s,o); d += __shfl_down(d,o); }
  if (lane==0){ asrc[n*8+hh]=s; adst[n*8+hh]=d; }
}

// ---------------- CSR-ordered per-node softmax ----------------
__global__ __launch_bounds__(256) void k_softmax(
    const int* __restrict__ srcs, const float* __restrict__ eas,
    const int* __restrict__ offs,
    const float* __restrict__ asrc, const float* __restrict__ adst,
    const float* __restrict__ wedot, const float* __restrict__ la,
    float* __restrict__ exn, float* __restrict__ aselfn,
    int N, int self_flag){
  int n = blockIdx.x*4 + (threadIdx.x>>6);
  if (n>=N) return;
  int lane = threadIdx.x&63;
  int hh = lane&7, esub = lane>>3;
  int beg = offs[n], end = offs[n+1];
  float wd = wedot[hh];
  float adn = adst[n*8+hh];

  float mx = -1e30f;
  for (int p0=beg; p0<end; p0+=8){
    int p = p0 + esub;
    if (p<end){
      int s = srcs[p];
      float a = asrc[s*8+hh] + adn + eas[p]*wd;
      a = a>0.f ? a : 0.2f*a;
      exn[(size_t)p*8+hh] = a;
      mx = fmaxf(mx, a);
    }
  }
  float aself = 0.f;
  if (self_flag){
    float a = asrc[n*8+hh] + adn + la[n]*wd;
    aself = a>0.f ? a : 0.2f*a;
    if (esub==0) mx = fmaxf(mx, aself);
  }
  mx = fmaxf(mx, __shfl_xor(mx, 8));
  mx = fmaxf(mx, __shfl_xor(mx, 16));
  mx = fmaxf(mx, __shfl_xor(mx, 32));

  float sum = 0.f;
  for (int p0=beg; p0<end; p0+=8){
    int p = p0 + esub;
    if (p<end){
      float x = __expf(exn[(size_t)p*8+hh] - mx);
      exn[(size_t)p*8+hh] = x;
      sum += x;
    }
  }
  float xs = 0.f;
  if (self_flag && esub==0){ xs = __expf(aself - mx); sum += xs; }
  sum += __shfl_xor(sum, 8);
  sum += __shfl_xor(sum, 16);
  sum += __shfl_xor(sum, 32);
  float inv = 1.f/(sum + 1e-16f);

  for (int p0=beg; p0<end; p0+=8){
    int p = p0 + esub;
    if (p<end) exn[(size_t)p*8+hh] *= inv;
  }
  if (self_flag && esub==0) aselfn[n*8+hh] = xs*inv;
}

// ---------------- aggregate: wave per (node, head-quad), float4 lanes -------
__global__ __launch_bounds__(256) void k_aggregate(const float* __restrict__ h,
    const float* __restrict__ exn, const int* __restrict__ srcs,
    const int* __restrict__ offs, const float* __restrict__ bias,
    const float* __restrict__ aselfn, float* __restrict__ out,
    u16* __restrict__ outb,
    int N, int relu_flag, int self_flag){
  int gw = blockIdx.x*4 + (threadIdx.x>>6);
  if (gw >= 2*N) return;
  int n = gw>>1, hq = gw&1;
  int lane = threadIdx.x&63;
  int sub = lane>>4;
  int coff = hq*256 + lane*4;
  int beg = offs[n], end = offs[n+1];
  float4 acc = make_float4(0.f,0.f,0.f,0.f);
  int p = beg;
  for (; p+2<=end; p+=2){
    int s0 = srcs[p], s1 = srcs[p+1];
    float e0 = exn[(size_t)p*8 + hq*4 + sub];
    float e1 = exn[(size_t)(p+1)*8 + hq*4 + sub];
    float4 h0 = *(const float4*)(h + (size_t)s0*512 + coff);
    float4 h1 = *(const float4*)(h + (size_t)s1*512 + coff);
    acc.x = fmaf(e0,h0.x, fmaf(e1,h1.x, acc.x));
    acc.y = fmaf(e0,h0.y, fmaf(e1,h1.y, acc.y));
    acc.z = fmaf(e0,h0.z, fmaf(e1,h1.z, acc.z));
    acc.w = fmaf(e0,h0.w, fmaf(e1,h1.w, acc.w));
  }
  if (p<end){
    int s0 = srcs[p];
    float e0 = exn[(size_t)p*8 + hq*4 + sub];
    float4 h0 = *(const float4*)(h + (size_t)s0*512 + coff);
    acc.x = fmaf(e0,h0.x,acc.x); acc.y = fmaf(e0,h0.y,acc.y);
    acc.z = fmaf(e0,h0.z,acc.z); acc.w = fmaf(e0,h0.w,acc.w);
  }
  if (self_flag){
    float es = aselfn[n*8 + hq*4 + sub];
    float4 hv = *(const float4*)(h + (size_t)n*512 + coff);
    acc.x = fmaf(es,hv.x,acc.x); acc.y = fmaf(es,hv.y,acc.y);
    acc.z = fmaf(es,hv.z,acc.z); acc.w = fmaf(es,hv.w,acc.w);
  }
  float4 bv = *(const float4*)(bias + coff);
  float4 v = make_float4(acc.x+bv.x, acc.y+bv.y, acc.z+bv.z, acc.w+bv.w);
  if (relu_flag){
    v.x=fmaxf(v.x,0.f); v.y=fmaxf(v.y,0.f); v.z=fmaxf(v.z,0.f); v.w=fmaxf(v.w,0.f);
  }
  if (outb){
    ushort4 o; o.x=f2b(v.x); o.y=f2b(v.y); o.z=f2b(v.z); o.w=f2b(v.w);
    *(ushort4*)(outb + (size_t)n*512 + coff) = o;
  } else {
    *(float4*)(out + (size_t)n*512 + coff) = v;
  }
}

// column mean: 512 threads (one per channel), each block covers 16 rows
__global__ __launch_bounds__(512) void k_colmean(const float* __restrict__ out2, float* __restrict__ o,
                          int N, float invN){
  int c = threadIdx.x;
  int n0 = blockIdx.x*16;
  int nend = min(n0+16, N);
  float s = 0.f;
  for (int n=n0;n<nend;++n) s += out2[(size_t)n*512 + c];
  atomicAdd(&o[c], s*invN);
}

extern "C" void kernel_launch(void* const* d_in, const int* in_sizes, int n_in,
                              void* d_out, int out_size, void* d_ws, size_t ws_size,
                              hipStream_t stream){
  const float* x   = (const float*)d_in[0];
  const int* eidx  = (const int*)d_in[1];
  const float* ea  = (const float*)d_in[2];
  const float* W1  = (const float*)d_in[3];
  const float* We1 = (const float*)d_in[4];
  const float* as1 = (const float*)d_in[5];
  const float* ad1 = (const float*)d_in[6];
  const float* ae1 = (const float*)d_in[7];
  const float* b1  = (const float*)d_in[8];
  const float* W2  = (const float*)d_in[9];
  const float* We2 = (const float*)d_in[10];
  const float* as2 = (const float*)d_in[11];
  const float* ad2 = (const float*)d_in[12];
  const float* ae2 = (const float*)d_in[13];
  const float* b2  = (const float*)d_in[14];
  float* outp = (float*)d_out;

  const int FIN = 128, D1 = 512;
  const int N = in_sizes[0]/FIN;
  const int E = in_sizes[1]/2;
  const int* srcA = eidx;
  const int* dstA = eidx + E;

  char* ws = (char*)d_ws;
  size_t o = 0;
  auto alloc = [&](size_t bytes)->void*{
    void* p = ws + o; o = (o + bytes + 255) & ~(size_t)255; return p;
  };
  float* h1    = (float*)alloc((size_t)N*D1*4);   // layer1 features; reused as out2
  float* h2    = (float*)alloc((size_t)N*D1*4);
  u16*   out1rb= (u16*)  alloc((size_t)N*D1*2);   // relu(layer1 out), bf16
  u16*   xb    = (u16*)  alloc((size_t)N*FIN*2);
  u16*   W1t   = (u16*)  alloc((size_t)D1*FIN*2); // [512][128]
  u16*   W2t   = (u16*)  alloc((size_t)D1*D1*2);  // [512][512]
  float* exn   = (float*)alloc((size_t)E*8*4);
  int*   srcs  = (int*)  alloc((size_t)E*4);
  float* eas   = (float*)alloc((size_t)E*4);
  int*   offs  = (int*)  alloc((size_t)(N+1)*4);
  size_t zbeg = o;
  int*   cnt   = (int*)  alloc((size_t)N*4);
  int*   fill  = (int*)  alloc((size_t)N*4);
  float* easum = (float*)alloc((size_t)N*4);
  size_t zend = o;
  float* asrc  = (float*)alloc((size_t)N*8*4);
  float* adst  = (float*)alloc((size_t)N*8*4);
  float* la    = (float*)alloc((size_t)N*4);
  float* aselfn= (float*)alloc((size_t)N*8*4);
  float* wedot = (float*)alloc(64);
  (void)ws_size; (void)n_in;

  hipMemsetAsync(ws + zbeg, 0, zend - zbeg, stream);
  hipMemsetAsync(d_out, 0, (size_t)out_size*sizeof(float), stream);

  dim3 b256(256);
  int ge = (E+255)/256;
  int gn4 = (N+3)/4;

  // CSR build + casts + weight transposes
  k_count   <<<ge, b256, 0, stream>>>(dstA, ea, cnt, easum, E);
  k_scan    <<<1, 1024, 0, stream>>>(cnt, offs, N);
  k_scatter <<<ge, b256, 0, stream>>>(srcA, dstA, ea, offs, fill, srcs, eas, E);
  k_loopattr<<<(N+255)/256, b256, 0, stream>>>(cnt, easum, la, N);
  k_wedot   <<<2, 512, 0, stream>>>(We1, ae1, We2, ae2, wedot);
  k_cast_bf16<<<((N*FIN/4)+255)/256, b256, 0, stream>>>(x, xb, N*FIN/4);
  k_transpose_cast<<<dim3(D1/64, FIN/64), b256, 0, stream>>>(W1, W1t, FIN, D1);
  k_transpose_cast<<<dim3(D1/64, D1/64),  b256, 0, stream>>>(W2, W2t, D1, D1);

  // ---- layer 1 (no self loops) ----
  k_gemm_mfma<<<dim3(D1/64, (N+127)/128), b256, 0, stream>>>(xb, W1t, h1, N, D1, FIN);
  k_alpha_nodes<<<N, 512, 0, stream>>>(h1, as1, ad1, asrc, adst, N);
  k_softmax<<<gn4, b256, 0, stream>>>(srcs, eas, offs, asrc, adst, wedot, la,
                                      exn, aselfn, N, 0);
  k_aggregate<<<(2*N+3)/4, b256, 0, stream>>>(h1, exn, srcs, offs, b1,
                                              (const float*)nullptr, (float*)nullptr,
                                              out1rb, N, 1, 0);

  // ---- layer 2 (self loops, fill='mean') ----
  k_gemm_mfma<<<dim3(D1/64, (N+127)/128), b256, 0, stream>>>(out1rb, W2t, h2, N, D1, D1);
  k_alpha_nodes<<<N, 512, 0, stream>>>(h2, as2, ad2, asrc, adst, N);
  k_softmax<<<gn4, b256, 0, stream>>>(srcs, eas, offs, asrc, adst, wedot+8, la,
                                      exn, aselfn, N, 1);
  k_aggregate<<<(2*N+3)/4, b256, 0, stream>>>(h2, exn, srcs, offs, b2,
                                              aselfn, h1 /*out2*/, (u16*)nullptr, N, 0, 1);

  // ---- mean over nodes ----
  k_colmean<<<(N+15)/16, 512, 0, stream>>>(h1, outp, N, 1.0f/(float)N);
}

// Round 5
// 195.019 us; speedup vs baseline: 4.4494x; 1.2986x over previous
//
#include <hip/hip_runtime.h>
#include <hip/hip_bf16.h>

#define HD __device__ __forceinline__
typedef unsigned short u16;
typedef __attribute__((ext_vector_type(8))) short bf16x8;
typedef __attribute__((ext_vector_type(4))) float f32x4;

// round-to-nearest-even fp32 -> bf16 bits
HD u16 f2b(float f){
  unsigned u = __float_as_uint(f);
  unsigned r = (u + 0x7fffu + ((u>>16)&1u)) >> 16;
  return (u16)r;
}
HD float b2f(short s){ return __uint_as_float(((unsigned)(u16)s)<<16); }

// ---------------- CSR build ----------------
__global__ void k_count(const int* __restrict__ dst, const float* __restrict__ ea,
                        int* cnt, float* easum, int E){
  int e = blockIdx.x*blockDim.x + threadIdx.x;
  if (e>=E) return;
  int d = dst[e];
  atomicAdd(&cnt[d],1);
  atomicAdd(&easum[d], ea[e]);
}

// two-level scan, one block
__global__ __launch_bounds__(1024) void k_scan(const int* __restrict__ cnt, int* offs, int N){
  __shared__ int lds[1024];
  const int chunk = (N + 1023)/1024;
  const int b = threadIdx.x*chunk;
  int s = 0;
  for (int i=0;i<chunk;++i){ int idx=b+i; if (idx<N) s += cnt[idx]; }
  lds[threadIdx.x] = s;
  __syncthreads();
  #pragma unroll
  for (int off=1; off<1024; off<<=1){
    int t = (threadIdx.x>=(unsigned)off)? lds[threadIdx.x-off] : 0;
    __syncthreads();
    lds[threadIdx.x] += t;
    __syncthreads();
  }
  int excl = lds[threadIdx.x] - s;
  for (int i=0;i<chunk;++i){
    int idx=b+i;
    if (idx<N){ offs[idx] = excl; excl += cnt[idx]; }
  }
  if (threadIdx.x==1023) offs[N] = lds[1023];
}

__global__ void k_scatter(const int* __restrict__ src, const int* __restrict__ dst,
                          const float* __restrict__ ea, const int* __restrict__ offs,
                          int* fill, int* srcs, float* eas, int E){
  int e = blockIdx.x*blockDim.x + threadIdx.x;
  if (e>=E) return;
  int d = dst[e];
  int p = offs[d] + atomicAdd(&fill[d],1);
  srcs[p] = src[e];
  eas[p]  = ea[e];
}

__global__ void k_loopattr(const int* __restrict__ cnt, const float* __restrict__ easum,
                           float* la, int N){
  int n = blockIdx.x*blockDim.x + threadIdx.x;
  if (n>=N) return;
  la[n] = easum[n] / fmaxf((float)cnt[n], 1.f);
}

__global__ __launch_bounds__(512) void k_wedot(const float* __restrict__ We1, const float* __restrict__ ae1,
                        const float* __restrict__ We2, const float* __restrict__ ae2,
                        float* wedot){
  int which = blockIdx.x;
  const float* We = which? We2 : We1;
  const float* ae = which? ae2 : ae1;
  int hh = threadIdx.x>>6, lane = threadIdx.x&63;
  float p = We[hh*64+lane]*ae[hh*64+lane];
  #pragma unroll
  for (int o=32;o;o>>=1) p += __shfl_down(p,o);
  if (lane==0) wedot[which*8+hh] = p;
}

// ---------------- casts ----------------
__global__ void k_cast_bf16(const float* __restrict__ in, u16* __restrict__ out, int total4){
  int i = (blockIdx.x*blockDim.x + threadIdx.x);
  if (i>=total4) return;
  float4 v = *(const float4*)(in + (size_t)i*4);
  ushort4 o; o.x=f2b(v.x); o.y=f2b(v.y); o.z=f2b(v.z); o.w=f2b(v.w);
  *(ushort4*)(out + (size_t)i*4) = o;
}

// W[K][N] fp32 -> Wt[N][K] bf16, 64x64 tiles
__global__ __launch_bounds__(256) void k_transpose_cast(const float* __restrict__ W,
                                                        u16* __restrict__ Wt, int K, int N){
  __shared__ float T[64][65];
  int k0 = blockIdx.y*64, n0 = blockIdx.x*64;
  #pragma unroll
  for (int i=0;i<16;++i){
    int id = i*256 + threadIdx.x;
    int r = id>>6, c = id&63;
    T[r][c] = W[(size_t)(k0+r)*N + n0 + c];
  }
  __syncthreads();
  #pragma unroll
  for (int i=0;i<16;++i){
    int id = i*256 + threadIdx.x;
    int rr = id>>6, cc = id&63;
    Wt[(size_t)(n0+rr)*K + k0 + cc] = f2b(T[cc][rr]);
  }
}

// ---------------- bf16 MFMA GEMM: Cb[M,N] = A[M,K] @ Bt[N,K]^T (bf16 out) ---
// tile 128x64, BK=32, 256 threads = 4 waves in 2x2
__global__ __launch_bounds__(256) void k_gemm_mfma(
    const u16* __restrict__ A, const u16* __restrict__ Bt,
    u16* __restrict__ Cb, int M, int N, int K){
  __shared__ char lds[(128+64)*80];   // row stride 80B (20 dwords) - conflict-free
  char* As = lds;
  char* Bs = lds + 128*80;
  const int tid = threadIdx.x;
  const int lane = tid & 63, w = tid >> 6;
  const int wr = w >> 1, wc = w & 1;
  const int l15 = lane & 15, l4 = lane >> 4;
  const int m0 = blockIdx.y*128, n0 = blockIdx.x*64;

  f32x4 acc[4][2] = {};
  int aoff[4], boff[2];
  #pragma unroll
  for (int i=0;i<4;++i) aoff[i] = (wr*64 + i*16 + l15)*80 + l4*16;
  #pragma unroll
  for (int j=0;j<2;++j) boff[j] = (wc*32 + j*16 + l15)*80 + l4*16;

  for (int k0=0; k0<K; k0+=32){
    #pragma unroll
    for (int i=0;i<2;++i){
      int cid = tid*2+i;
      int r = cid>>2, c = cid&3;
      int row = m0 + r;
      float4 v = make_float4(0.f,0.f,0.f,0.f);
      if (row < M) v = *(const float4*)(A + (size_t)row*K + k0 + c*8);
      *(float4*)(As + r*80 + c*16) = v;
    }
    {
      int r = tid>>2, c = tid&3;
      float4 v = *(const float4*)(Bt + (size_t)(n0+r)*K + k0 + c*8);
      *(float4*)(Bs + r*80 + c*16) = v;
    }
    __syncthreads();
    bf16x8 a[4], b[2];
    #pragma unroll
    for (int i=0;i<4;++i) a[i] = *reinterpret_cast<const bf16x8*>(As + aoff[i]);
    #pragma unroll
    for (int j=0;j<2;++j) b[j] = *reinterpret_cast<const bf16x8*>(Bs + boff[j]);
    #pragma unroll
    for (int i=0;i<4;++i)
      #pragma unroll
      for (int j=0;j<2;++j)
        acc[i][j] = __builtin_amdgcn_mfma_f32_16x16x32_bf16(a[i], b[j], acc[i][j], 0,0,0);
    __syncthreads();
  }
  // epilogue: C[row][col], row=(lane>>4)*4+reg, col=lane&15
  #pragma unroll
  for (int i=0;i<4;++i){
    #pragma unroll
    for (int j=0;j<2;++j){
      #pragma unroll
      for (int r=0;r<4;++r){
        int row = m0 + wr*64 + i*16 + l4*4 + r;
        int col = n0 + wc*32 + j*16 + l15;
        if (row < M) Cb[(size_t)row*N + col] = f2b(acc[i][j][r]);
      }
    }
  }
}

// alpha_src[n,h], alpha_dst[n,h] from bf16 h; one wave per node (4/block)
__global__ __launch_bounds__(256) void k_alpha_nodes(const u16* __restrict__ hb,
    const float* __restrict__ a_s, const float* __restrict__ a_d,
    float* asrc, float* adst, int N){
  int n = blockIdx.x*4 + (threadIdx.x>>6);
  if (n>=N) return;
  int lane = threadIdx.x&63;
  int c0 = lane*8;
  bf16x8 v = *(const bf16x8*)(hb + (size_t)n*512 + c0);
  float s = 0.f, d = 0.f;
  #pragma unroll
  for (int j=0;j<8;++j){
    float f = b2f(v[j]);
    s = fmaf(f, a_s[c0+j], s);
    d = fmaf(f, a_d[c0+j], d);
  }
  // reduce across the 8 lanes of this head-group (lanes h*8..h*8+7)
  #pragma unroll
  for (int o=1;o<8;o<<=1){ s += __shfl_xor(s,o); d += __shfl_xor(d,o); }
  if ((lane&7)==0){ int hh = lane>>3; asrc[n*8+hh]=s; adst[n*8+hh]=d; }
}

// ---------------- CSR-ordered per-node softmax (2 passes) ----------------
// writes UNNORMALIZED exp into exn, 1/(sum+eps) into inv, raw self-exp into aselfx
__global__ __launch_bounds__(256) void k_softmax(
    const int* __restrict__ srcs, const float* __restrict__ eas,
    const int* __restrict__ offs,
    const float* __restrict__ asrc, const float* __restrict__ adst,
    const float* __restrict__ wedot, const float* __restrict__ la,
    float* __restrict__ exn, float* __restrict__ inv, float* __restrict__ aselfx,
    int N, int self_flag){
  int n = blockIdx.x*4 + (threadIdx.x>>6);
  if (n>=N) return;
  int lane = threadIdx.x&63;
  int hh = lane&7, esub = lane>>3;
  int beg = offs[n], end = offs[n+1];
  float wd = wedot[hh];
  float adn = adst[n*8+hh];

  float mx = -1e30f;
  for (int p0=beg; p0<end; p0+=8){
    int p = p0 + esub;
    if (p<end){
      int s = srcs[p];
      float a = asrc[s*8+hh] + adn + eas[p]*wd;
      a = a>0.f ? a : 0.2f*a;
      exn[(size_t)p*8+hh] = a;
      mx = fmaxf(mx, a);
    }
  }
  float aself = 0.f;
  if (self_flag){
    float a = asrc[n*8+hh] + adn + la[n]*wd;
    aself = a>0.f ? a : 0.2f*a;
    if (esub==0) mx = fmaxf(mx, aself);
  }
  mx = fmaxf(mx, __shfl_xor(mx, 8));
  mx = fmaxf(mx, __shfl_xor(mx, 16));
  mx = fmaxf(mx, __shfl_xor(mx, 32));

  float sum = 0.f;
  for (int p0=beg; p0<end; p0+=8){
    int p = p0 + esub;
    if (p<end){
      float x = __expf(exn[(size_t)p*8+hh] - mx);
      exn[(size_t)p*8+hh] = x;
      sum += x;
    }
  }
  float xs = 0.f;
  if (self_flag && esub==0){ xs = __expf(aself - mx); sum += xs; }
  sum += __shfl_xor(sum, 8);
  sum += __shfl_xor(sum, 16);
  sum += __shfl_xor(sum, 32);
  if (esub==0){
    inv[n*8+hh] = 1.f/(sum + 1e-16f);
    if (self_flag) aselfx[n*8+hh] = xs;
  }
}

// ---------------- aggregate: ONE wave per node, bf16 full-row gather --------
// lane covers channels lane*8..lane*8+7 (head = lane>>3); normalization folded in
__global__ __launch_bounds__(256) void k_aggregate(const u16* __restrict__ hb,
    const float* __restrict__ exn, const int* __restrict__ srcs,
    const int* __restrict__ offs, const float* __restrict__ bias,
    const float* __restrict__ inv, const float* __restrict__ aselfx,
    float* __restrict__ outf, u16* __restrict__ outb,
    int N, int relu_flag, int self_flag){
  int n = blockIdx.x*4 + (threadIdx.x>>6);
  if (n>=N) return;
  int lane = threadIdx.x&63;
  int hh = lane>>3;
  int c0 = lane*8;
  int beg = offs[n], end = offs[n+1];
  float acc[8] = {};
  int p = beg;
  for (; p+2<=end; p+=2){
    int s0 = srcs[p], s1 = srcs[p+1];
    float e0 = exn[(size_t)p*8 + hh];
    float e1 = exn[(size_t)(p+1)*8 + hh];
    bf16x8 v0 = *(const bf16x8*)(hb + (size_t)s0*512 + c0);
    bf16x8 v1 = *(const bf16x8*)(hb + (size_t)s1*512 + c0);
    #pragma unroll
    for (int j=0;j<8;++j)
      acc[j] = fmaf(e0, b2f(v0[j]), fmaf(e1, b2f(v1[j]), acc[j]));
  }
  if (p<end){
    int s0 = srcs[p];
    float e0 = exn[(size_t)p*8 + hh];
    bf16x8 v0 = *(const bf16x8*)(hb + (size_t)s0*512 + c0);
    #pragma unroll
    for (int j=0;j<8;++j) acc[j] = fmaf(e0, b2f(v0[j]), acc[j]);
  }
  if (self_flag){
    float es = aselfx[n*8+hh];
    bf16x8 v = *(const bf16x8*)(hb + (size_t)n*512 + c0);
    #pragma unroll
    for (int j=0;j<8;++j) acc[j] = fmaf(es, b2f(v[j]), acc[j]);
  }
  float iv = inv[n*8+hh];
  float val[8];
  #pragma unroll
  for (int j=0;j<8;++j){
    val[j] = acc[j]*iv + bias[c0+j];
    if (relu_flag) val[j] = fmaxf(val[j], 0.f);
  }
  if (outb){
    bf16x8 ov;
    #pragma unroll
    for (int j=0;j<8;++j) ov[j] = (short)f2b(val[j]);
    *(bf16x8*)(outb + (size_t)n*512 + c0) = ov;
  } else {
    *(float4*)(outf + (size_t)n*512 + c0)     = make_float4(val[0],val[1],val[2],val[3]);
    *(float4*)(outf + (size_t)n*512 + c0 + 4) = make_float4(val[4],val[5],val[6],val[7]);
  }
}

// column mean: 512 threads (one per channel), each block covers 16 rows
__global__ __launch_bounds__(512) void k_colmean(const float* __restrict__ out2, float* __restrict__ o,
                          int N, float invN){
  int c = threadIdx.x;
  int n0 = blockIdx.x*16;
  int nend = min(n0+16, N);
  float s = 0.f;
  for (int n=n0;n<nend;++n) s += out2[(size_t)n*512 + c];
  atomicAdd(&o[c], s*invN);
}

extern "C" void kernel_launch(void* const* d_in, const int* in_sizes, int n_in,
                              void* d_out, int out_size, void* d_ws, size_t ws_size,
                              hipStream_t stream){
  const float* x   = (const float*)d_in[0];
  const int* eidx  = (const int*)d_in[1];
  const float* ea  = (const float*)d_in[2];
  const float* W1  = (const float*)d_in[3];
  const float* We1 = (const float*)d_in[4];
  const float* as1 = (const float*)d_in[5];
  const float* ad1 = (const float*)d_in[6];
  const float* ae1 = (const float*)d_in[7];
  const float* b1  = (const float*)d_in[8];
  const float* W2  = (const float*)d_in[9];
  const float* We2 = (const float*)d_in[10];
  const float* as2 = (const float*)d_in[11];
  const float* ad2 = (const float*)d_in[12];
  const float* ae2 = (const float*)d_in[13];
  const float* b2  = (const float*)d_in[14];
  float* outp = (float*)d_out;

  const int FIN = 128, D1 = 512;
  const int N = in_sizes[0]/FIN;
  const int E = in_sizes[1]/2;
  const int* srcA = eidx;
  const int* dstA = eidx + E;

  char* ws = (char*)d_ws;
  size_t o = 0;
  auto alloc = [&](size_t bytes)->void*{
    void* p = ws + o; o = (o + bytes + 255) & ~(size_t)255; return p;
  };
  u16*   hb1   = (u16*)  alloc((size_t)N*D1*2);   // layer1 features, bf16
  u16*   hb2   = (u16*)  alloc((size_t)N*D1*2);   // layer2 features, bf16
  u16*   out1rb= (u16*)  alloc((size_t)N*D1*2);   // relu(layer1 out), bf16
  float* out2  = (float*)alloc((size_t)N*D1*4);   // layer2 out, fp32
  u16*   xb    = (u16*)  alloc((size_t)N*FIN*2);
  u16*   W1t   = (u16*)  alloc((size_t)D1*FIN*2); // [512][128]
  u16*   W2t   = (u16*)  alloc((size_t)D1*D1*2);  // [512][512]
  float* exn   = (float*)alloc((size_t)E*8*4);
  int*   srcs  = (int*)  alloc((size_t)E*4);
  float* eas   = (float*)alloc((size_t)E*4);
  int*   offs  = (int*)  alloc((size_t)(N+1)*4);
  size_t zbeg = o;
  int*   cnt   = (int*)  alloc((size_t)N*4);
  int*   fill  = (int*)  alloc((size_t)N*4);
  float* easum = (float*)alloc((size_t)N*4);
  size_t zend = o;
  float* asrc  = (float*)alloc((size_t)N*8*4);
  float* adst  = (float*)alloc((size_t)N*8*4);
  float* la    = (float*)alloc((size_t)N*4);
  float* inv   = (float*)alloc((size_t)N*8*4);
  float* aselfx= (float*)alloc((size_t)N*8*4);
  float* wedot = (float*)alloc(64);
  (void)ws_size; (void)n_in;

  hipMemsetAsync(ws + zbeg, 0, zend - zbeg, stream);
  hipMemsetAsync(d_out, 0, (size_t)out_size*sizeof(float), stream);

  dim3 b256(256);
  int ge = (E+255)/256;
  int gn4 = (N+3)/4;

  // CSR build + casts + weight transposes
  k_count   <<<ge, b256, 0, stream>>>(dstA, ea, cnt, easum, E);
  k_scan    <<<1, 1024, 0, stream>>>(cnt, offs, N);
  k_scatter <<<ge, b256, 0, stream>>>(srcA, dstA, ea, offs, fill, srcs, eas, E);
  k_loopattr<<<(N+255)/256, b256, 0, stream>>>(cnt, easum, la, N);
  k_wedot   <<<2, 512, 0, stream>>>(We1, ae1, We2, ae2, wedot);
  k_cast_bf16<<<((N*FIN/4)+255)/256, b256, 0, stream>>>(x, xb, N*FIN/4);
  k_transpose_cast<<<dim3(D1/64, FIN/64), b256, 0, stream>>>(W1, W1t, FIN, D1);
  k_transpose_cast<<<dim3(D1/64, D1/64),  b256, 0, stream>>>(W2, W2t, D1, D1);

  // ---- layer 1 (no self loops) ----
  k_gemm_mfma<<<dim3(D1/64, (N+127)/128), b256, 0, stream>>>(xb, W1t, hb1, N, D1, FIN);
  k_alpha_nodes<<<gn4, b256, 0, stream>>>(hb1, as1, ad1, asrc, adst, N);
  k_softmax<<<gn4, b256, 0, stream>>>(srcs, eas, offs, asrc, adst, wedot, la,
                                      exn, inv, aselfx, N, 0);
  k_aggregate<<<gn4, b256, 0, stream>>>(hb1, exn, srcs, offs, b1, inv,
                                        (const float*)nullptr, (float*)nullptr,
                                        out1rb, N, 1, 0);

  // ---- layer 2 (self loops, fill='mean') ----
  k_gemm_mfma<<<dim3(D1/64, (N+127)/128), b256, 0, stream>>>(out1rb, W2t, hb2, N, D1, D1);
  k_alpha_nodes<<<gn4, b256, 0, stream>>>(hb2, as2, ad2, asrc, adst, N);
  k_softmax<<<gn4, b256, 0, stream>>>(srcs, eas, offs, asrc, adst, wedot+8, la,
                                      exn, inv, aselfx, N, 1);
  k_aggregate<<<gn4, b256, 0, stream>>>(hb2, exn, srcs, offs, b2, inv,
                                        aselfx, out2, (u16*)nullptr, N, 0, 1);

  // ---- mean over nodes ----
  k_colmean<<<(N+15)/16, 512, 0, stream>>>(out2, outp, N, 1.0f/(float)N);
}